// Round 5
// baseline (302.883 us; speedup 1.0000x reference)
//
#include <hip/hip_runtime.h>
#include <hip/hip_fp16.h>

// Problem constants (match reference)
constexpr int IMG_ = 256;
constexpr int M_   = 1920;   // N_SHOTS * N_SAMPLES
constexpr int B_   = 64;
constexpr int MI_  = M_ * IMG_;          // 491520 elements per phase table
constexpr int IMG2 = IMG_ * IMG_;        // 65536

typedef _Float16 half8 __attribute__((ext_vector_type(8)));
typedef float floatx16 __attribute__((ext_vector_type(16)));

// Async 16B global->LDS copy. LDS dest = wave-uniform base + lane*16.
__device__ inline void gl_lds16(const void* g, void* l) {
  __builtin_amdgcn_global_load_lds(
      (const __attribute__((address_space(1))) unsigned int*)g,
      (__attribute__((address_space(3))) unsigned int*)l, 16, 0, 0);
}

// Bank-swizzle: physical 16B-chunk slot p at row r holds logical chunk
// cl = (p - (r>>1)) & 3.  Frag read of logical chunk k at row r uses
// p = ((r>>1) + k) & 3  ->  bank base (16r + 4p) mod 32 covers all 32 banks
// over any 8 consecutive rows (conflict-floor ds_read_b128).

// ---------------------------------------------------------------------------
// Phase tables, natural layout [m][i] (f16)
// ---------------------------------------------------------------------------
__global__ __launch_bounds__(256) void phase1_k(
    const float* __restrict__ samples,
    _Float16* __restrict__ axh_r, _Float16* __restrict__ axh_i,
    _Float16* __restrict__ ayh_r, _Float16* __restrict__ ayh_i) {
  int idx = blockIdx.x * 256 + threadIdx.x;
  if (idx >= MI_) return;
  int m = idx >> 8;
  int i = idx & 255;
  float g  = (float)i - 128.0f;
  float kx = samples[2 * m + 0];
  float ky = samples[2 * m + 1];
  float sx, cx, sy, cy;
  sincospif(-2.0f * kx * g, &sx, &cx);
  sincospif(-2.0f * ky * g, &sy, &cy);
  axh_r[idx] = (_Float16)cx; axh_i[idx] = (_Float16)sx;
  ayh_r[idx] = (_Float16)cy; ayh_i[idx] = (_Float16)sy;
}

// Transposed, pre-conjugated tables [pixel][m] (f16) for the adjoint pass.
__global__ __launch_bounds__(256) void phase2_k(
    const float* __restrict__ samples,
    _Float16* __restrict__ axtc_r, _Float16* __restrict__ axtc_i,
    _Float16* __restrict__ aytc_r, _Float16* __restrict__ aytc_i) {
  int m = blockIdx.x * 256 + threadIdx.x;
  if (m >= M_) return;
  int i = blockIdx.y;
  float g  = (float)i - 128.0f;
  float kx = samples[2 * m + 0];
  float ky = samples[2 * m + 1];
  float sx, cx, sy, cy;
  sincospif(-2.0f * kx * g, &sx, &cx);
  sincospif(-2.0f * ky * g, &sy, &cy);
  int o = i * M_ + m;
  axtc_r[o] = (_Float16)cx; axtc_i[o] = (_Float16)(-sx);  // conj(Ax)^T
  aytc_r[o] = (_Float16)cy; aytc_i[o] = (_Float16)(-sy);  // conj(Ay)^T
}

// ---------------------------------------------------------------------------
// X f32 -> f16, natural layout
// ---------------------------------------------------------------------------
__global__ __launch_bounds__(256) void xcvt_k(
    const float* __restrict__ xr, const float* __restrict__ xi,
    _Float16* __restrict__ xh_r, _Float16* __restrict__ xh_i) {
  int idx = (blockIdx.x * 256 + threadIdx.x) * 8;
  float4 a = *(const float4*)&xr[idx];
  float4 c = *(const float4*)&xr[idx + 4];
  half8 h;
  h[0] = (_Float16)a.x; h[1] = (_Float16)a.y; h[2] = (_Float16)a.z; h[3] = (_Float16)a.w;
  h[4] = (_Float16)c.x; h[5] = (_Float16)c.y; h[6] = (_Float16)c.z; h[7] = (_Float16)c.w;
  *(half8*)&xh_r[idx] = h;
  a = *(const float4*)&xi[idx];
  c = *(const float4*)&xi[idx + 4];
  h[0] = (_Float16)a.x; h[1] = (_Float16)a.y; h[2] = (_Float16)a.z; h[3] = (_Float16)a.w;
  h[4] = (_Float16)c.x; h[5] = (_Float16)c.y; h[6] = (_Float16)c.z; h[7] = (_Float16)c.w;
  *(half8*)&xh_i[idx] = h;
}

// ---------------------------------------------------------------------------
// Forward NDFT, j-first contraction:
//   V[m,i] = sum_j Ay[m,j] * X_b[i,j]   (MFMA GEMM, K = j = 256)
//   K[m]   = sum_i Ax[m,i] * V[m,i]     (epilogue weighted reduce)
// Block 256 thr = 4 waves (2x2 of 64m x 64i); 128 m-rows/block, i in 2 halves.
// Double-buffered LDS, one barrier per K-step, conflict-floor bank swizzle.
// ---------------------------------------------------------------------------
__global__ __launch_bounds__(256, 2) void fwd_k(
    const _Float16* __restrict__ axh_r, const _Float16* __restrict__ axh_i,
    const _Float16* __restrict__ ayh_r, const _Float16* __restrict__ ayh_i,
    const _Float16* __restrict__ xh_r, const _Float16* __restrict__ xh_i,
    const float* __restrict__ density,
    _Float16* __restrict__ kwh_r, _Float16* __restrict__ kwh_i) {
  __shared__ _Float16 sA[2][2 * 128 * 32];   // Ay tile: [buf][re|im][128m x 32j]
  __shared__ _Float16 sB[2][2 * 128 * 32];   // X tile:  [buf][re|im][128i x 32j]
  __shared__ float kred[2][128][2];          // [i-wave-half][m-local][re/im]

  const int t  = threadIdx.x;
  const int w  = t >> 6, l = t & 63;
  const int lo = l & 31, hi = l >> 5;
  const int mw  = (w & 1) * 64;
  const int iwb = w >> 1;
  const int iw  = iwb * 64;
  const int m0 = blockIdx.x * 128;
  const int b  = blockIdx.y;

  ((float*)kred)[t]       = 0.f;
  ((float*)kred)[t + 256] = 0.f;

  const _Float16* __restrict__ xbr = xh_r + (size_t)b * IMG2;
  const _Float16* __restrict__ xbi = xh_i + (size_t)b * IMG2;

  const floatx16 z16 = {0.f,0.f,0.f,0.f,0.f,0.f,0.f,0.f,0.f,0.f,0.f,0.f,0.f,0.f,0.f,0.f};
  floatx16 accr[2][2], acci[2][2];

  auto stage = [&](int kt, int buf, int ic) {
    const int j0 = kt * 32;
#pragma unroll
    for (int p = 0; p < 2; ++p) {
      int s  = w * 2 + p;              // slice 0..7 (wave-uniform)
      int q  = s * 64 + l;             // slot 0..511
      int r  = q >> 2;                 // tile row
      int cl = ((q & 3) - ((q >> 3) & 3)) & 3;   // logical chunk for phys slot
      int ga = (m0 + r) * IMG_ + j0 + cl * 8;
      int gb = (ic * 128 + r) * IMG_ + j0 + cl * 8;
      gl_lds16(ayh_r + ga, &sA[buf][s * 512]);
      gl_lds16(ayh_i + ga, &sA[buf][4096 + s * 512]);
      gl_lds16(xbr + gb,  &sB[buf][s * 512]);
      gl_lds16(xbi + gb,  &sB[buf][4096 + s * 512]);
    }
  };

  auto compute = [&](int buf) {
#pragma unroll
    for (int ks = 0; ks < 2; ++ks) {
      const int k = ks * 2 + hi;
      half8 ar[2], ai[2], nai[2], br[2], bi[2];
#pragma unroll
      for (int tm = 0; tm < 2; ++tm) {
        int rt  = mw + tm * 32 + lo;
        int off = rt * 32 + ((( rt >> 1) + k) & 3) * 8;
        ar[tm]  = *(const half8*)&sA[buf][off];
        ai[tm]  = *(const half8*)&sA[buf][4096 + off];
        nai[tm] = -ai[tm];
      }
#pragma unroll
      for (int ti = 0; ti < 2; ++ti) {
        int rt  = iw + ti * 32 + lo;
        int off = rt * 32 + ((( rt >> 1) + k) & 3) * 8;
        br[ti]  = *(const half8*)&sB[buf][off];
        bi[ti]  = *(const half8*)&sB[buf][4096 + off];
      }
#pragma unroll
      for (int tm = 0; tm < 2; ++tm)
#pragma unroll
        for (int ti = 0; ti < 2; ++ti) {
          accr[tm][ti] = __builtin_amdgcn_mfma_f32_32x32x16_f16(ar[tm],  br[ti], accr[tm][ti], 0, 0, 0);
          accr[tm][ti] = __builtin_amdgcn_mfma_f32_32x32x16_f16(nai[tm], bi[ti], accr[tm][ti], 0, 0, 0);
          acci[tm][ti] = __builtin_amdgcn_mfma_f32_32x32x16_f16(ar[tm],  bi[ti], acci[tm][ti], 0, 0, 0);
          acci[tm][ti] = __builtin_amdgcn_mfma_f32_32x32x16_f16(ai[tm],  br[ti], acci[tm][ti], 0, 0, 0);
        }
    }
  };

  for (int ic = 0; ic < 2; ++ic) {
#pragma unroll
    for (int tm = 0; tm < 2; ++tm)
#pragma unroll
      for (int ti = 0; ti < 2; ++ti) { accr[tm][ti] = z16; acci[tm][ti] = z16; }

    stage(0, 0, ic);
    for (int kt = 0; kt < 8; kt += 2) {
      __syncthreads();                 // drains buf0's loads
      stage(kt + 1, 1, ic);
      compute(0);
      __syncthreads();                 // drains buf1's loads
      if (kt + 2 < 8) stage(kt + 2, 0, ic);
      compute(1);
    }

    // Epilogue: kred[m] += sum_i Ax[m,i] * V[m,i]
#pragma unroll
    for (int tm = 0; tm < 2; ++tm) {
#pragma unroll
      for (int reg = 0; reg < 16; ++reg) {
        int row = (reg & 3) + 8 * (reg >> 2) + 4 * hi;
        int m = m0 + mw + tm * 32 + row;
        float wr = 0.f, wi = 0.f;
#pragma unroll
        for (int ti = 0; ti < 2; ++ti) {
          int i = ic * 128 + iw + ti * 32 + lo;
          float xr_ = (float)axh_r[m * IMG_ + i];
          float xi_ = (float)axh_i[m * IMG_ + i];
          float tr = accr[tm][ti][reg], tv = acci[tm][ti][reg];
          wr = fmaf(xr_, tr, fmaf(-xi_, tv, wr));
          wi = fmaf(xr_, tv, fmaf(xi_, tr, wi));
        }
#pragma unroll
        for (int off = 1; off < 32; off <<= 1) {
          wr += __shfl_xor(wr, off);
          wi += __shfl_xor(wi, off);
        }
        if (lo == 0) {
          int ml = mw + tm * 32 + row;
          kred[iwb][ml][0] += wr;
          kred[iwb][ml][1] += wi;
        }
      }
    }
  }

  __syncthreads();
  if (t < 128) {
    int m = m0 + t;
    float rr = kred[0][t][0] + kred[1][t][0];
    float ii = kred[0][t][1] + kred[1][t][1];
    float d  = density[m];
    kwh_r[b * M_ + m] = (_Float16)(rr * d);
    kwh_i[b * M_ + m] = (_Float16)(ii * d);
  }
}

// ---------------------------------------------------------------------------
// Adjoint NDFT: out[b,i,j] = (1/IMG^2) sum_m [conj(Ax)[m,i]*kw[b,m]]*conj(Ay)[m,j]
// Tile 128i x 64j, 256 thr = 4 waves (2 iw x 2 jw of 64i x 32j). Grid
// (2,4,64) = 512 blocks -> 2 blocks/CU (LDS 48KB). ONE barrier per K-step:
// A' global loads reg-pipelined across the compute window; B via gl_lds.
// ---------------------------------------------------------------------------
__global__ __launch_bounds__(256, 2) void adj_k(
    const _Float16* __restrict__ axtc_r, const _Float16* __restrict__ axtc_i,
    const _Float16* __restrict__ aytc_r, const _Float16* __restrict__ aytc_i,
    const _Float16* __restrict__ kwh_r, const _Float16* __restrict__ kwh_i,
    float* __restrict__ out) {
  __shared__ _Float16 sA[2][2 * 128 * 32];   // A' = conj(Ax)^T * kw
  __shared__ _Float16 sB[2][2 * 64 * 32];    // conj(Ay)^T

  const int t  = threadIdx.x;
  const int w  = t >> 6, l = t & 63;
  const int lo = l & 31, hi = l >> 5;
  const int iw = (w & 1) * 64;
  const int jw = (w >> 1) * 32;
  const int i0 = blockIdx.x * 128;
  const int j0 = blockIdx.y * 64;
  const int b  = blockIdx.z;

  const floatx16 z16 = {0.f,0.f,0.f,0.f,0.f,0.f,0.f,0.f,0.f,0.f,0.f,0.f,0.f,0.f,0.f,0.f};
  floatx16 accr[2] = {z16, z16};
  floatx16 acci[2] = {z16, z16};

  half8 pxr[2], pxi[2], pkr[2], pki[2];   // A' pipeline registers

  auto loadA = [&](int mt) {
    const int m0 = mt * 32;
#pragma unroll
    for (int s = 0; s < 2; ++s) {
      int rs = t + s * 256;                 // row-slot 0..511 (128 rows x 4)
      int r  = rs >> 2, p = rs & 3;
      int cl = (p - (r >> 1)) & 3;
      int ga = (i0 + r) * M_ + m0 + cl * 8;
      pxr[s] = *(const half8*)&axtc_r[ga];
      pxi[s] = *(const half8*)&axtc_i[ga];
      pkr[s] = *(const half8*)&kwh_r[b * M_ + m0 + cl * 8];
      pki[s] = *(const half8*)&kwh_i[b * M_ + m0 + cl * 8];
    }
  };
  auto writeA = [&](int buf) {
#pragma unroll
    for (int s = 0; s < 2; ++s) {
      int rs = t + s * 256;
      half8 wr8 = pxr[s] * pkr[s] - pxi[s] * pki[s];
      half8 wi8 = pxr[s] * pki[s] + pxi[s] * pkr[s];
      *(half8*)&sA[buf][rs * 8]        = wr8;
      *(half8*)&sA[buf][4096 + rs * 8] = wi8;
    }
  };
  auto stageB = [&](int mt, int buf) {
    const int m0 = mt * 32;
#pragma unroll
    for (int p2 = 0; p2 < 2; ++p2) {
      int sl = w * 2 + p2;                  // slice 0..7 (wave-uniform)
      int q  = sl * 64 + l;                 // 0..511
      int arr = q >> 8;
      int qq  = q & 255;
      int r   = qq >> 2, p = qq & 3;
      int cl  = (p - (r >> 1)) & 3;
      int gb  = (j0 + r) * M_ + m0 + cl * 8;
      const _Float16* src = arr ? aytc_i : aytc_r;
      gl_lds16(src + gb, &sB[buf][sl * 512]);
    }
  };
  auto compute = [&](int buf) {
#pragma unroll
    for (int ks = 0; ks < 2; ++ks) {
      const int k = ks * 2 + hi;
      half8 ar[2], ai[2], nai[2], br, bi;
#pragma unroll
      for (int tm = 0; tm < 2; ++tm) {
        int rt  = iw + tm * 32 + lo;
        int off = rt * 32 + (((rt >> 1) + k) & 3) * 8;
        ar[tm]  = *(const half8*)&sA[buf][off];
        ai[tm]  = *(const half8*)&sA[buf][4096 + off];
        nai[tm] = -ai[tm];
      }
      {
        int rt  = jw + lo;
        int off = rt * 32 + (((rt >> 1) + k) & 3) * 8;
        br = *(const half8*)&sB[buf][off];
        bi = *(const half8*)&sB[buf][2048 + off];
      }
#pragma unroll
      for (int tm = 0; tm < 2; ++tm) {
        accr[tm] = __builtin_amdgcn_mfma_f32_32x32x16_f16(ar[tm],  br, accr[tm], 0, 0, 0);
        accr[tm] = __builtin_amdgcn_mfma_f32_32x32x16_f16(nai[tm], bi, accr[tm], 0, 0, 0);
        acci[tm] = __builtin_amdgcn_mfma_f32_32x32x16_f16(ar[tm],  bi, acci[tm], 0, 0, 0);
        acci[tm] = __builtin_amdgcn_mfma_f32_32x32x16_f16(ai[tm],  br, acci[tm], 0, 0, 0);
      }
    }
  };

  loadA(0);
  stageB(0, 0);
  writeA(0);
  for (int mt = 0; mt < M_ / 32; ++mt) {
    const int cur = mt & 1, nxt = cur ^ 1;
    __syncthreads();                 // lands A'(mt) writes + B(mt) gl_lds
    if (mt + 1 < M_ / 32) {
      loadA(mt + 1);                 // global->VGPR, hidden by compute below
      stageB(mt + 1, nxt);           // gl_lds, drains at next barrier
    }
    compute(cur);
    if (mt + 1 < M_ / 32) writeA(nxt);  // f16 mul + ds_write (buf not in use)
  }

  const float s = 1.0f / (float)IMG2;
#pragma unroll
  for (int tm = 0; tm < 2; ++tm)
#pragma unroll
    for (int reg = 0; reg < 16; ++reg) {
      int row = (reg & 3) + 8 * (reg >> 2) + 4 * hi;
      int ig = i0 + iw + tm * 32 + row;
      int jg = j0 + jw + lo;
      float2 v = make_float2(accr[tm][reg] * s, acci[tm][reg] * s);
      *(float2*)&out[((size_t)(b * IMG_ + ig) * IMG_ + jg) * 2] = v;
    }
}

// ---------------------------------------------------------------------------
// Launch
// ---------------------------------------------------------------------------
extern "C" void kernel_launch(void* const* d_in, const int* in_sizes, int n_in,
                              void* d_out, int out_size, void* d_ws, size_t ws_size,
                              hipStream_t stream) {
  (void)in_sizes; (void)n_in; (void)out_size; (void)ws_size;

  const float* xr      = (const float*)d_in[0];
  const float* xi      = (const float*)d_in[1];
  const float* samples = (const float*)d_in[2];
  const float* density = (const float*)d_in[3];
  float* out = (float*)d_out;

  _Float16* f = (_Float16*)d_ws;
  _Float16* axh_r  = f + 0 * MI_;
  _Float16* axh_i  = f + 1 * MI_;
  _Float16* ayh_r  = f + 2 * MI_;
  _Float16* ayh_i  = f + 3 * MI_;
  _Float16* axtc_r = f + 4 * MI_;
  _Float16* axtc_i = f + 5 * MI_;
  _Float16* aytc_r = f + 6 * MI_;
  _Float16* aytc_i = f + 7 * MI_;
  _Float16* kwh_r  = f + 8 * MI_;
  _Float16* kwh_i  = kwh_r + B_ * M_;

  // X (f16, natural layout) parked in d_out; consumed by fwd_k before adj_k
  // overwrites d_out with the final result.
  _Float16* xh_r = (_Float16*)d_out;
  _Float16* xh_i = xh_r + (size_t)B_ * IMG2;

  phase1_k<<<(MI_ + 255) / 256, 256, 0, stream>>>(samples, axh_r, axh_i, ayh_r, ayh_i);
  phase2_k<<<dim3(8, IMG_), 256, 0, stream>>>(samples, axtc_r, axtc_i, aytc_r, aytc_i);
  xcvt_k<<<(B_ * IMG2) / 8 / 256, 256, 0, stream>>>(xr, xi, xh_r, xh_i);
  fwd_k<<<dim3(M_ / 128, B_), 256, 0, stream>>>(axh_r, axh_i, ayh_r, ayh_i,
                                                xh_r, xh_i, density, kwh_r, kwh_i);
  adj_k<<<dim3(2, 4, B_), 256, 0, stream>>>(axtc_r, axtc_i, aytc_r, aytc_i,
                                            kwh_r, kwh_i, out);
}